// Round 12
// baseline (168.538 us; speedup 1.0000x reference)
//
#include <hip/hip_runtime.h>
#include <cmath>

// FFA regressor for MI355X — 3 dispatches: std_partial, passA_all, passB_all.
// R12 = R11 with passA at 128 threads/block, CHB=2 (HB doubles): circular-window
// prologue (+6 reads per stage-pair) amortizes over 2x columns -> stage LDS reads
// -17%, index VALU likewise. Wave-local fence structure unchanged (wave span =
// 128 rows >= 64-row groups). Uniform S0=8, radix-4 in-place fused stages,
// swz bank-swizzle, zero-block elision. passB/std unchanged from R11.

constexpr int NSEQ    = 32;
constexpr int NLEN    = 262144;
constexpr int OUTROWS = 81920;
constexpr int STDCH   = 32;

constexpr int cilog2(int v) { int r = 0; while (v > 1) { v >>= 1; ++r; } return r; }

// scratch offsets per config, in bf16 elements (sizes: 32 * 2^K * CPAD)
constexpr size_t SCROFF[8] = {0, 6291456, 12582912, 18874368,
                              27262976, 29360128, 31981568, 34603008};

__device__ __forceinline__ unsigned bf16rne(float f) {
    unsigned u = __float_as_uint(f);
    return (u + 0x7FFFu + ((u >> 16) & 1u)) >> 16;
}
__device__ __forceinline__ unsigned pk2(float lo, float hi) {
    return bf16rne(lo) | (bf16rne(hi) << 16);
}
// bank swizzle for passA rows: bits 2-4 ^= bits 4-6 (bijective, quad-contiguous)
__device__ __forceinline__ int swz(int r) { return r ^ (((r >> 4) & 7) << 2); }

// wave-level fence (R10-proven)
__device__ __forceinline__ void wfence()
{
    __builtin_amdgcn_sched_barrier(0);
    asm volatile("s_waitcnt lgkmcnt(0)" ::: "memory");
    __builtin_amdgcn_sched_barrier(0);
    __builtin_amdgcn_wave_barrier();
}
template<bool BAR>
__device__ __forceinline__ void stsync()
{
    if constexpr (BAR) __syncthreads();
    else wfence();
}

// ---------------- std partials ----------------
__global__ __launch_bounds__(256)
void std_partial(const float* __restrict__ x, float2* __restrict__ part)
{
    const int seq = blockIdx.x, ch = blockIdx.y;
    constexpr int N4 = NLEN / 4 / STDCH;
    const float4* xp = reinterpret_cast<const float4*>(x + (size_t)seq * NLEN) + (size_t)ch * N4;
    float s = 0.f, s2 = 0.f;
    for (int i = threadIdx.x; i < N4; i += 256) {
        float4 v = xp[i];
        s  += (v.x + v.y) + (v.z + v.w);
        s2 += (v.x * v.x + v.y * v.y) + (v.z * v.z + v.w * v.w);
    }
    #pragma unroll
    for (int off = 32; off > 0; off >>= 1) {
        s  += __shfl_down(s, off, 64);
        s2 += __shfl_down(s2, off, 64);
    }
    __shared__ float2 ws[4];
    const int w = threadIdx.x >> 6, l = threadIdx.x & 63;
    if (l == 0) ws[w] = make_float2(s, s2);
    __syncthreads();
    if (threadIdx.x == 0) {
        float a = ws[0].x + ws[1].x + ws[2].x + ws[3].x;
        float b = ws[0].y + ws[1].y + ws[2].y + ws[3].y;
        part[seq * STDCH + ch] = make_float2(a, b);
    }
}

// ---------------- pass A: fused stages (1,2), contiguous float4 reads ----------------
template<int BINS, int G, int HB, bool BAR>
__device__ __forceinline__
void fusedA1ip(float* __restrict__ buf, int Q, int c0)
{
    constexpr int CST = G + 4;
    const int r4 = swz(4 * Q);
    float4 ff[HB + 3];
    #pragma unroll
    for (int j = 0; j < HB + 3; ++j) {
        int cc = c0 - 3 + j;
        if (cc < 0) cc += BINS;
        if (cc >= BINS) cc -= BINS;
        ff[j] = *reinterpret_cast<const float4*>(&buf[cc * CST + r4]);
    }
    stsync<BAR>();
    #pragma unroll
    for (int i = 0; i < HB; ++i) {
        const int c = c0 + i;
        if (c < BINS) {
            float4 f = ff[i + 3], fm1 = ff[i + 2], fm2 = ff[i + 1], fm3 = ff[i];
            float u0 = f.x + f.y;
            float u1 = f.x + fm1.y;
            float4 o;
            o.x = u0 + (f.z + f.w);
            o.y = u0 + (fm1.z + fm1.w);
            o.z = u1 + (fm1.z + fm2.w);
            o.w = u1 + (fm2.z + fm3.w);
            *reinterpret_cast<float4*>(&buf[c * CST + r4]) = o;
        }
    }
    stsync<BAR>();
}

// ---------------- pass A: fused stages (s, s+1), in-place ----------------
template<int BINS, int G, int HB, bool BAR>
__device__ __forceinline__
void fusedAip(float* __restrict__ buf, int s, int Q, int c0)
{
    constexpr int CST = G + 4;
    const int h = 1 << (s - 1), S = 1 << s;
    const int q  = Q & (h - 1);
    const int G2 = (Q >> (s - 1)) << (s + 1);
    const int rA0 = swz(G2 + q),     rA1 = swz(G2 + q + h);
    const int rB0 = swz(G2 + S + q), rB1 = swz(G2 + S + q + h);
    const int vo  = swz(G2 + 4 * q);
    auto mbf = [](int x) { int r = x % BINS; return r < 0 ? r + BINS : r; };
    const int ba1 = mbf(c0 - q - 1);
    const int bb0 = mbf(c0 - 2 * q - 2);
    const int bb1 = mbf(c0 - 3 * q - 3);

    float fa0[HB], fa1[HB + 1], fb0[HB + 2], fb1[HB + 3];
    #pragma unroll
    for (int i = 0; i < HB; ++i) {
        int cc = c0 + i; if (cc >= BINS) cc = BINS - 1;
        fa0[i] = buf[cc * CST + rA0];
    }
    int idx = ba1;
    #pragma unroll
    for (int i = 0; i < HB + 1; ++i) {
        fa1[i] = buf[idx * CST + rA1];
        ++idx; if (idx == BINS) idx = 0;
    }
    idx = bb0;
    #pragma unroll
    for (int i = 0; i < HB + 2; ++i) {
        fb0[i] = buf[idx * CST + rB0];
        ++idx; if (idx == BINS) idx = 0;
    }
    idx = bb1;
    #pragma unroll
    for (int i = 0; i < HB + 3; ++i) {
        fb1[i] = buf[idx * CST + rB1];
        ++idx; if (idx == BINS) idx = 0;
    }
    stsync<BAR>();
    #pragma unroll
    for (int i = 0; i < HB; ++i) {
        const int c = c0 + i;
        if (c < BINS) {
            float u0 = fa0[i] + fa1[i + 1];
            float u1 = fa0[i] + fa1[i];
            float v0c  = fb0[i + 2] + fb1[i + 3];
            float v0p  = fb0[i + 1] + fb1[i + 2];
            float v1p  = fb0[i + 1] + fb1[i + 1];
            float v1pp = fb0[i]     + fb1[i];
            float4 o; o.x = u0 + v0c; o.y = u0 + v0p; o.z = u1 + v1p; o.w = u1 + v1pp;
            *reinterpret_cast<float4*>(&buf[c * CST + vo]) = o;
        }
    }
    stsync<BAR>();
}

// ---------------- pass A body (S0=8, G=256, 128 threads, CHB=2) ----------------
template<int DS, int BINS, int K, int CPAD>
__device__ __forceinline__
void passA_body(float* __restrict__ buf, const float* __restrict__ xs,
                unsigned short* __restrict__ scrC, int R, int blk, int sl)
{
    constexpr int S0    = 8;
    constexpr int G     = 256;
    constexpr int M     = 1 << (K - S0);
    constexpr int CST   = G + 4;
    constexpr int QPW   = 32;             // quads per wave (128-row span)
    constexpr int HB    = (BINS + 1) / 2; // CHB = 2
    const int t = threadIdx.x;

    const int fmax = max(0, min(G * BINS, R * BINS - blk * G * BINS));
    if (fmax <= 0) return;   // fully-zero block: passB zero-fills v >= ceil(R/G)

    // coalesced init (exact w=0.5 downsample)
    if constexpr (DS == 2) {
        const float4* src4 = reinterpret_cast<const float4*>(xs + 2 * (size_t)blk * G * BINS);
        constexpr int NF4 = G * BINS / 2;
        for (int i = t; i < NF4; i += 128) {
            const int f0 = 2 * i;
            if (f0 < fmax) {
                float4 v = src4[i];
                int lr = f0 / BINS, c = f0 - lr * BINS;
                buf[c * CST + swz(lr)] = 0.5f * (v.x + v.y);
                if (f0 + 1 < fmax) {
                    int c1 = c + 1, lr1 = lr;
                    if (c1 == BINS) { c1 = 0; ++lr1; }
                    buf[c1 * CST + swz(lr1)] = 0.5f * (v.z + v.w);
                }
            }
        }
    } else {
        const float4* src4 = reinterpret_cast<const float4*>(xs + 4 * (size_t)blk * G * BINS);
        constexpr int NF4 = G * BINS;
        for (int i = t; i < NF4; i += 128) {
            if (i < fmax) {
                float4 v = src4[i];
                int lr = i / BINS, c = i - lr * BINS;
                buf[c * CST + swz(lr)] = 0.5f * (v.y + v.z);
            }
        }
    }
    for (int f = fmax + t; f < G * BINS; f += 128) {
        int lr = f / BINS, c = f - lr * BINS;
        buf[c * CST + swz(lr)] = 0.f;
    }
    __syncthreads();

    // wave-local mapping: wave w owns quads [32w, 32w+32) = rows [128w, 128w+128)
    {
        const int w = t >> 6, l = t & 63;
        const int Q  = w * QPW + (l >> 1);     // CHB=2
        const int c0 = (l & 1) * HB;
        // groups: (1,2)->4, (3,4)->16, (5,6)->64 rows: wave-local; (7,8)->256: block
        fusedA1ip<BINS, G, HB, false>(buf, Q, c0);
        fusedAip <BINS, G, HB, false>(buf, 3, Q, c0);
        fusedAip <BINS, G, HB, false>(buf, 5, Q, c0);
        __syncthreads();
        fusedAip <BINS, G, HB, true >(buf, 7, Q, c0);
    }

    // bf16 writeout: 2 rows per thread, contiguous G*CPAD run per block
    #pragma unroll
    for (int it = 0; it < 2; ++it) {
        const int rn = t + it * 128;
        const int lr = swz(rn);
        unsigned u[CPAD / 2];
        #pragma unroll
        for (int k = 0; k < CPAD / 2; ++k) {
            const int ca = 2 * k, cbn = 2 * k + 1;
            float fa = (ca < BINS)  ? buf[ca * CST + lr]  : 0.f;
            float fb = (cbn < BINS) ? buf[cbn * CST + lr] : 0.f;
            u[k] = pk2(fa, fb);
        }
        unsigned short* dst = scrC + ((size_t)(sl * M + blk) * G + rn) * CPAD;
        if constexpr (CPAD == 16) {
            uint4* d4 = reinterpret_cast<uint4*>(dst);
            d4[0] = make_uint4(u[0], u[1], u[2], u[3]);
            d4[1] = make_uint4(u[4], u[5], u[6], u[7]);
        } else {
            uint2* d2 = reinterpret_cast<uint2*>(dst);
            #pragma unroll
            for (int k = 0; k < CPAD / 4; ++k)
                d2[k] = make_uint2(u[2 * k], u[2 * k + 1]);
        }
    }
}

__global__ __launch_bounds__(128, 4)
void passA_all(const float* __restrict__ x, unsigned short* __restrict__ scr)
{
    __shared__ float buf[19 * 260];   // 19,760 B -> 8 blocks/CU (16 waves)
    const int b = blockIdx.x;
    if (b < 8192) {
        const int cfg = b >> 11, r = b & 2047, blk = r & 63, sl = r >> 6;
        const float* xs = x + (size_t)sl * NLEN;
        switch (cfg) {
            case 0: passA_body<2, 10, 14, 12>(buf, xs, scr + SCROFF[0], 13107, blk, sl); break;
            case 1: passA_body<2, 11, 14, 12>(buf, xs, scr + SCROFF[1], 11915, blk, sl); break;
            case 2: passA_body<2, 12, 14, 12>(buf, xs, scr + SCROFF[2], 10922, blk, sl); break;
            default: passA_body<2, 13, 14, 16>(buf, xs, scr + SCROFF[3], 10082, blk, sl); break;
        }
    } else {
        const int b2 = b - 8192;
        const int cfg = b2 >> 9, r = b2 & 511, blk = r & 15, sl = r >> 4;
        const float* xs = x + (size_t)sl * NLEN;
        switch (cfg) {
            case 0: passA_body<4, 16, 12, 16>(buf, xs, scr + SCROFF[4], 4096, blk, sl); break;
            case 1: passA_body<4, 17, 12, 20>(buf, xs, scr + SCROFF[5], 3855, blk, sl); break;
            case 2: passA_body<4, 18, 12, 20>(buf, xs, scr + SCROFF[6], 3640, blk, sl); break;
            default: passA_body<4, 19, 12, 20>(buf, xs, scr + SCROFF[7], 3449, blk, sl); break;
        }
    }
}

// ---------------- pass B (unchanged from R11) ----------------
template<int BINS, int M, int CST, int HB, int LQ>
__device__ __forceinline__
void fusedB(float* __restrict__ zpg, int s, int p, int sub)
{
    constexpr int QUADS = M / 4;
    const int Q   = sub & (QUADS - 1);
    const int chi = sub >> LQ;
    const int c0  = chi * HB;
    const int h = 1 << (s - 1), S = 1 << s;
    const int q  = Q & (h - 1);
    const int G2 = (Q >> (s - 1)) << (s + 1);
    const int rA0 = G2 + q, rA1 = rA0 + h, rB0 = G2 + S + q, rB1 = rB0 + h;
    const int vo = G2 + 4 * q;
    auto mbf = [](int x, int B) { int r = x % B; return r < 0 ? r + B : r; };
    const int ba1 = mbf(c0 - q - p * h - 1, BINS);
    const int bb0 = mbf(c0 - 2 * q - p * S - 2, BINS);
    const int bb1 = mbf(c0 - 3 * q - p * (S + h) - 3, BINS);

    float fa0[HB], fa1[HB + 1], fb0[HB + 2], fb1[HB + 3];
    #pragma unroll
    for (int i = 0; i < HB; ++i) {
        int cc = c0 + i; if (cc >= BINS) cc = BINS - 1;
        fa0[i] = zpg[cc * CST + rA0];
    }
    int idx = ba1;
    #pragma unroll
    for (int i = 0; i < HB + 1; ++i) {
        fa1[i] = zpg[idx * CST + rA1];
        ++idx; if (idx == BINS) idx = 0;
    }
    idx = bb0;
    #pragma unroll
    for (int i = 0; i < HB + 2; ++i) {
        fb0[i] = zpg[idx * CST + rB0];
        ++idx; if (idx == BINS) idx = 0;
    }
    idx = bb1;
    #pragma unroll
    for (int i = 0; i < HB + 3; ++i) {
        fb1[i] = zpg[idx * CST + rB1];
        ++idx; if (idx == BINS) idx = 0;
    }
    __syncthreads();
    #pragma unroll
    for (int i2 = 0; i2 < HB; ++i2) {
        const int c = c0 + i2;
        if (c < BINS) {
            float u0 = fa0[i2] + fa1[i2 + 1];
            float u1 = fa0[i2] + fa1[i2];
            float v0c  = fb0[i2 + 2] + fb1[i2 + 3];
            float v0p  = fb0[i2 + 1] + fb1[i2 + 2];
            float v1p  = fb0[i2 + 1] + fb1[i2 + 1];
            float v1pp = fb0[i2]     + fb1[i2];
            float4 o; o.x = u0 + v0c; o.y = u0 + v0p; o.z = u1 + v1p; o.w = u1 + v1pp;
            *reinterpret_cast<float4*>(&zpg[c * CST + vo]) = o;
        }
    }
    __syncthreads();
}

template<int BINS, int K, int P, int CPAD, int OUTOFF>
__device__ __forceinline__
void passB_body(float* __restrict__ zb, float* __restrict__ s_red,
                const unsigned short* __restrict__ scrC, const float2* __restrict__ part,
                float* __restrict__ out, int R, int p_base, int sl)
{
    constexpr int S0   = 8;
    constexpr int G    = 256;
    constexpr int M    = 1 << (K - S0);   // ds2:64, ds4:16
    constexpr int TS   = K - S0;          // ds2:6,  ds4:4  (always even)
    constexpr int CST  = M + 4;
    constexpr int BCST = BINS * CST;
    constexpr int SUBW = 512 / P;         // ds2:64, ds4:32
    constexpr int LSUB = cilog2(SUBW);
    constexpr int LQB  = cilog2(M / 4);
    constexpr int CHB  = SUBW / (M / 4);
    constexpr int HB   = (BINS + CHB - 1) / CHB;

    const int t = threadIdx.x;

    if (t < 64) {
        float s = 0.f, s2 = 0.f;
        if (t < 32) { float2 pp = part[sl * STDCH + t]; s = pp.x; s2 = pp.y; }
        #pragma unroll
        for (int off = 16; off > 0; off >>= 1) {
            s  += __shfl_down(s, off, 64);
            s2 += __shfl_down(s2, off, 64);
        }
        if (t == 0) {
            const float n = (float)NLEN;
            s_red[0] = rsqrtf((s2 - s * s / n) / (n - 1.f)) * rsqrtf((float)R);
        }
    }

    // gather; fully-zero blocks (v >= vmax) were skipped by passA -> zero-fill
    {
        constexpr int RUN = P * CPAD / 4;
        constexpr int TOT = M * RUN;
        const int vmax = (R + G - 1) >> S0;
        const unsigned short* base = scrC + (size_t)sl * M * G * CPAD + (size_t)p_base * CPAD;
        for (int i = t; i < TOT; i += 512) {
            const int v = i / RUN, r = i - v * RUN;
            uint2 d = make_uint2(0u, 0u);
            if (v < vmax)
                d = *reinterpret_cast<const uint2*>(base + (size_t)v * G * CPAD + 4 * r);
            const int e0 = 4 * r;
            const int pl = e0 / CPAD, c = e0 - pl * CPAD;
            float* zp = zb + pl * BCST + v;
            if (c + 0 < BINS) zp[(c + 0) * CST] = __uint_as_float(d.x << 16);
            if (c + 1 < BINS) zp[(c + 1) * CST] = __uint_as_float(d.x & 0xFFFF0000u);
            if (c + 2 < BINS) zp[(c + 2) * CST] = __uint_as_float(d.y << 16);
            if (c + 3 < BINS) zp[(c + 3) * CST] = __uint_as_float(d.y & 0xFFFF0000u);
        }
    }
    __syncthreads();

    const int sub = t & (SUBW - 1), pg = t >> LSUB;
    const int p = p_base + pg;
    float* zpg = zb + pg * BCST;
    #pragma unroll
    for (int s = 1; s <= TS; s += 2)
        fusedB<BINS, M, CST, HB, LQB>(zpg, s, p, sub);

    constexpr int ROWS = P * M;
    if (t < ROWS) {
        const int pg2 = t >> TS;
        const int v   = t & (M - 1);
        const float* z = zb + pg2 * BCST;
        float a[BINS];
        #pragma unroll
        for (int c = 0; c < BINS; ++c) a[c] = z[c * CST + v];
        float mx = a[0];
        #pragma unroll
        for (int c = 1; c < BINS; ++c) mx = fmaxf(mx, a[c]);
        constexpr int MIDX = (BINS - 1) / 2;
        #pragma unroll
        for (int i = 0; i <= MIDX; ++i) {
            #pragma unroll
            for (int j = i + 1; j < BINS; ++j) {
                float lo = fminf(a[i], a[j]);
                float hi = fmaxf(a[i], a[j]);
                a[i] = lo; a[j] = hi;
            }
        }
        out[(size_t)sl * OUTROWS + OUTOFF + (size_t)p_base * M + t] = (mx - a[MIDX]) * s_red[0];
    }
}

__global__ __launch_bounds__(512, 6)
void passB_all(const unsigned short* __restrict__ scr, const float2* __restrict__ part,
               float* __restrict__ out)
{
    __shared__ float zb[8 * 13 * 68];   // 28.3 KB (max: ds2 P=8, BINS=13, CST=68)
    __shared__ float s_red[1];
    const int b = blockIdx.x;
    if (b < 4096) {
        const int cfg = b >> 10, r = b & 1023, pb = r & 31, sl = r >> 5;
        const int p_base = pb * 8;
        switch (cfg) {
            case 0: passB_body<10, 14, 8, 12, 0>    (zb, s_red, scr + SCROFF[0], part, out, 13107, p_base, sl); break;
            case 1: passB_body<11, 14, 8, 12, 16384>(zb, s_red, scr + SCROFF[1], part, out, 11915, p_base, sl); break;
            case 2: passB_body<12, 14, 8, 12, 32768>(zb, s_red, scr + SCROFF[2], part, out, 10922, p_base, sl); break;
            default: passB_body<13, 14, 8, 16, 49152>(zb, s_red, scr + SCROFF[3], part, out, 10082, p_base, sl); break;
        }
    } else {
        const int b2 = b - 4096;
        const int cfg = b2 >> 9, r = b2 & 511, pb = r & 15, sl = r >> 4;
        const int p_base = pb * 16;
        switch (cfg) {
            case 0: passB_body<16, 12, 16, 16, 65536>(zb, s_red, scr + SCROFF[4], part, out, 4096, p_base, sl); break;
            case 1: passB_body<17, 12, 16, 20, 69632>(zb, s_red, scr + SCROFF[5], part, out, 3855, p_base, sl); break;
            case 2: passB_body<18, 12, 16, 20, 73728>(zb, s_red, scr + SCROFF[6], part, out, 3640, p_base, sl); break;
            default: passB_body<19, 12, 16, 20, 77824>(zb, s_red, scr + SCROFF[7], part, out, 3449, p_base, sl); break;
        }
    }
}

// ---------------- host ----------------
extern "C" void kernel_launch(void* const* d_in, const int* in_sizes, int n_in,
                              void* d_out, int out_size, void* d_ws, size_t ws_size,
                              hipStream_t stream)
{
    (void)in_sizes; (void)n_in; (void)out_size; (void)ws_size;
    const float* x = (const float*)d_in[0];
    float* out  = (float*)d_out;
    float* wsf  = (float*)d_ws;
    float2* part = reinterpret_cast<float2*>(wsf + 64);        // 1024 float2
    unsigned short* scr = reinterpret_cast<unsigned short*>(wsf + 2176);  // 74.5 MB used

    hipLaunchKernelGGL(std_partial, dim3(NSEQ, STDCH), dim3(256), 0, stream, x, part);
    hipLaunchKernelGGL(passA_all, dim3(10240), dim3(128), 0, stream, x, scr);
    hipLaunchKernelGGL(passB_all, dim3(6144), dim3(512), 0, stream, scr, part, out);
}

// Round 13
// 142.498 us; speedup vs baseline: 1.1827x; 1.1827x over previous
//
#include <hip/hip_runtime.h>
#include <cmath>

// FFA regressor for MI355X — 3 dispatches: std_partial, passA_all, passB_all.
// R13 = exact revert to R11 (measured best: 141.9 us).
// passA: uniform S0=8 (G=256), 256 threads, CHB=4; init + 4 radix-4 fused
// in-place stages (p=0 fusedB algebra), swz bank-swizzle, wave-local fences
// for stages (1,2),(3,4),(5,6), block barrier for (7,8); zero-block elision.
// passB: fused tail stages (TS even: 3x/2x fusedB) + fused max/median/SNR.

constexpr int NSEQ    = 32;
constexpr int NLEN    = 262144;
constexpr int OUTROWS = 81920;
constexpr int STDCH   = 32;

constexpr int cilog2(int v) { int r = 0; while (v > 1) { v >>= 1; ++r; } return r; }

// scratch offsets per config, in bf16 elements (sizes: 32 * 2^K * CPAD)
constexpr size_t SCROFF[8] = {0, 6291456, 12582912, 18874368,
                              27262976, 29360128, 31981568, 34603008};

__device__ __forceinline__ unsigned bf16rne(float f) {
    unsigned u = __float_as_uint(f);
    return (u + 0x7FFFu + ((u >> 16) & 1u)) >> 16;
}
__device__ __forceinline__ unsigned pk2(float lo, float hi) {
    return bf16rne(lo) | (bf16rne(hi) << 16);
}
// bank swizzle for passA rows: bits 2-4 ^= bits 4-6 (bijective, quad-contiguous)
__device__ __forceinline__ int swz(int r) { return r ^ (((r >> 4) & 7) << 2); }

// wave-level fence (R10-proven): lanes of this wave see this wave's LDS writes
__device__ __forceinline__ void wfence()
{
    __builtin_amdgcn_sched_barrier(0);
    asm volatile("s_waitcnt lgkmcnt(0)" ::: "memory");
    __builtin_amdgcn_sched_barrier(0);
    __builtin_amdgcn_wave_barrier();
}
template<bool BAR>
__device__ __forceinline__ void stsync()
{
    if constexpr (BAR) __syncthreads();
    else wfence();
}

// ---------------- std partials ----------------
__global__ __launch_bounds__(256)
void std_partial(const float* __restrict__ x, float2* __restrict__ part)
{
    const int seq = blockIdx.x, ch = blockIdx.y;
    constexpr int N4 = NLEN / 4 / STDCH;
    const float4* xp = reinterpret_cast<const float4*>(x + (size_t)seq * NLEN) + (size_t)ch * N4;
    float s = 0.f, s2 = 0.f;
    for (int i = threadIdx.x; i < N4; i += 256) {
        float4 v = xp[i];
        s  += (v.x + v.y) + (v.z + v.w);
        s2 += (v.x * v.x + v.y * v.y) + (v.z * v.z + v.w * v.w);
    }
    #pragma unroll
    for (int off = 32; off > 0; off >>= 1) {
        s  += __shfl_down(s, off, 64);
        s2 += __shfl_down(s2, off, 64);
    }
    __shared__ float2 ws[4];
    const int w = threadIdx.x >> 6, l = threadIdx.x & 63;
    if (l == 0) ws[w] = make_float2(s, s2);
    __syncthreads();
    if (threadIdx.x == 0) {
        float a = ws[0].x + ws[1].x + ws[2].x + ws[3].x;
        float b = ws[0].y + ws[1].y + ws[2].y + ws[3].y;
        part[seq * STDCH + ch] = make_float2(a, b);
    }
}

// ---------------- pass A: fused stages (1,2), contiguous float4 reads ----------------
template<int BINS, int G, int HB, bool BAR>
__device__ __forceinline__
void fusedA1ip(float* __restrict__ buf, int Q, int c0)
{
    constexpr int CST = G + 4;
    const int r4 = swz(4 * Q);
    float4 ff[HB + 3];
    #pragma unroll
    for (int j = 0; j < HB + 3; ++j) {
        int cc = c0 - 3 + j;
        if (cc < 0) cc += BINS;
        if (cc >= BINS) cc -= BINS;
        ff[j] = *reinterpret_cast<const float4*>(&buf[cc * CST + r4]);
    }
    stsync<BAR>();
    #pragma unroll
    for (int i = 0; i < HB; ++i) {
        const int c = c0 + i;
        if (c < BINS) {
            float4 f = ff[i + 3], fm1 = ff[i + 2], fm2 = ff[i + 1], fm3 = ff[i];
            float u0 = f.x + f.y;
            float u1 = f.x + fm1.y;
            float4 o;
            o.x = u0 + (f.z + f.w);
            o.y = u0 + (fm1.z + fm1.w);
            o.z = u1 + (fm1.z + fm2.w);
            o.w = u1 + (fm2.z + fm3.w);
            *reinterpret_cast<float4*>(&buf[c * CST + r4]) = o;
        }
    }
    stsync<BAR>();
}

// ---------------- pass A: fused stages (s, s+1), in-place ----------------
template<int BINS, int G, int HB, bool BAR>
__device__ __forceinline__
void fusedAip(float* __restrict__ buf, int s, int Q, int c0)
{
    constexpr int CST = G + 4;
    const int h = 1 << (s - 1), S = 1 << s;
    const int q  = Q & (h - 1);
    const int G2 = (Q >> (s - 1)) << (s + 1);
    const int rA0 = swz(G2 + q),     rA1 = swz(G2 + q + h);
    const int rB0 = swz(G2 + S + q), rB1 = swz(G2 + S + q + h);
    const int vo  = swz(G2 + 4 * q);
    auto mbf = [](int x) { int r = x % BINS; return r < 0 ? r + BINS : r; };
    const int ba1 = mbf(c0 - q - 1);
    const int bb0 = mbf(c0 - 2 * q - 2);
    const int bb1 = mbf(c0 - 3 * q - 3);

    float fa0[HB], fa1[HB + 1], fb0[HB + 2], fb1[HB + 3];
    #pragma unroll
    for (int i = 0; i < HB; ++i) {
        int cc = c0 + i; if (cc >= BINS) cc = BINS - 1;
        fa0[i] = buf[cc * CST + rA0];
    }
    int idx = ba1;
    #pragma unroll
    for (int i = 0; i < HB + 1; ++i) {
        fa1[i] = buf[idx * CST + rA1];
        ++idx; if (idx == BINS) idx = 0;
    }
    idx = bb0;
    #pragma unroll
    for (int i = 0; i < HB + 2; ++i) {
        fb0[i] = buf[idx * CST + rB0];
        ++idx; if (idx == BINS) idx = 0;
    }
    idx = bb1;
    #pragma unroll
    for (int i = 0; i < HB + 3; ++i) {
        fb1[i] = buf[idx * CST + rB1];
        ++idx; if (idx == BINS) idx = 0;
    }
    stsync<BAR>();
    #pragma unroll
    for (int i = 0; i < HB; ++i) {
        const int c = c0 + i;
        if (c < BINS) {
            float u0 = fa0[i] + fa1[i + 1];
            float u1 = fa0[i] + fa1[i];
            float v0c  = fb0[i + 2] + fb1[i + 3];
            float v0p  = fb0[i + 1] + fb1[i + 2];
            float v1p  = fb0[i + 1] + fb1[i + 1];
            float v1pp = fb0[i]     + fb1[i];
            float4 o; o.x = u0 + v0c; o.y = u0 + v0p; o.z = u1 + v1p; o.w = u1 + v1pp;
            *reinterpret_cast<float4*>(&buf[c * CST + vo]) = o;
        }
    }
    stsync<BAR>();
}

// ---------------- pass A body (uniform: S0=8, G=256, 256 threads) ----------------
template<int DS, int BINS, int K, int CPAD>
__device__ __forceinline__
void passA_body(float* __restrict__ buf, const float* __restrict__ xs,
                unsigned short* __restrict__ scrC, int R, int blk, int sl)
{
    constexpr int S0    = 8;
    constexpr int G     = 256;
    constexpr int M     = 1 << (K - S0);
    constexpr int CST   = G + 4;
    constexpr int QUADS = G / 4;          // 64
    constexpr int CHB   = 4;              // 256 threads / 64 quads
    constexpr int LCHB  = 2;
    constexpr int QPW   = QUADS / 4;      // 16 quads per wave (64-row span)
    constexpr int HB    = (BINS + CHB - 1) / CHB;
    const int t = threadIdx.x;

    const int fmax = max(0, min(G * BINS, R * BINS - blk * G * BINS));
    if (fmax <= 0) return;   // fully-zero block: passB zero-fills v >= ceil(R/G)

    // coalesced init (exact w=0.5 downsample)
    if constexpr (DS == 2) {
        const float4* src4 = reinterpret_cast<const float4*>(xs + 2 * (size_t)blk * G * BINS);
        constexpr int NF4 = G * BINS / 2;
        for (int i = t; i < NF4; i += 256) {
            const int f0 = 2 * i;
            if (f0 < fmax) {
                float4 v = src4[i];
                int lr = f0 / BINS, c = f0 - lr * BINS;
                buf[c * CST + swz(lr)] = 0.5f * (v.x + v.y);
                if (f0 + 1 < fmax) {
                    int c1 = c + 1, lr1 = lr;
                    if (c1 == BINS) { c1 = 0; ++lr1; }
                    buf[c1 * CST + swz(lr1)] = 0.5f * (v.z + v.w);
                }
            }
        }
    } else {
        const float4* src4 = reinterpret_cast<const float4*>(xs + 4 * (size_t)blk * G * BINS);
        constexpr int NF4 = G * BINS;
        for (int i = t; i < NF4; i += 256) {
            if (i < fmax) {
                float4 v = src4[i];
                int lr = i / BINS, c = i - lr * BINS;
                buf[c * CST + swz(lr)] = 0.5f * (v.y + v.z);
            }
        }
    }
    for (int f = fmax + t; f < G * BINS; f += 256) {
        int lr = f / BINS, c = f - lr * BINS;
        buf[c * CST + swz(lr)] = 0.f;
    }
    __syncthreads();

    // wave-local mapping: wave w owns quads [w*16, w*16+16) = rows [64w, 64w+64)
    {
        const int w = t >> 6, l = t & 63;
        const int Q  = w * QPW + (l >> LCHB);
        const int c0 = (l & (CHB - 1)) * HB;
        // groups: (1,2)->4, (3,4)->16, (5,6)->64 rows: wave-local; (7,8)->256: block
        fusedA1ip<BINS, G, HB, false>(buf, Q, c0);
        fusedAip <BINS, G, HB, false>(buf, 3, Q, c0);
        fusedAip <BINS, G, HB, false>(buf, 5, Q, c0);
        __syncthreads();
        fusedAip <BINS, G, HB, true >(buf, 7, Q, c0);
    }

    // bf16 writeout: one full row per thread, contiguous G*CPAD run per block
    {
        const int lr = swz(t);
        unsigned u[CPAD / 2];
        #pragma unroll
        for (int k = 0; k < CPAD / 2; ++k) {
            const int ca = 2 * k, cbn = 2 * k + 1;
            float fa = (ca < BINS)  ? buf[ca * CST + lr]  : 0.f;
            float fb = (cbn < BINS) ? buf[cbn * CST + lr] : 0.f;
            u[k] = pk2(fa, fb);
        }
        unsigned short* dst = scrC + ((size_t)(sl * M + blk) * G + t) * CPAD;
        if constexpr (CPAD == 16) {
            uint4* d4 = reinterpret_cast<uint4*>(dst);
            d4[0] = make_uint4(u[0], u[1], u[2], u[3]);
            d4[1] = make_uint4(u[4], u[5], u[6], u[7]);
        } else {
            uint2* d2 = reinterpret_cast<uint2*>(dst);
            #pragma unroll
            for (int k = 0; k < CPAD / 4; ++k)
                d2[k] = make_uint2(u[2 * k], u[2 * k + 1]);
        }
    }
}

__global__ __launch_bounds__(256, 8)
void passA_all(const float* __restrict__ x, unsigned short* __restrict__ scr)
{
    __shared__ float buf[19 * 260];   // 19,760 B -> 8 blocks/CU (wave-capped)
    const int b = blockIdx.x;
    if (b < 8192) {
        const int cfg = b >> 11, r = b & 2047, blk = r & 63, sl = r >> 6;
        const float* xs = x + (size_t)sl * NLEN;
        switch (cfg) {
            case 0: passA_body<2, 10, 14, 12>(buf, xs, scr + SCROFF[0], 13107, blk, sl); break;
            case 1: passA_body<2, 11, 14, 12>(buf, xs, scr + SCROFF[1], 11915, blk, sl); break;
            case 2: passA_body<2, 12, 14, 12>(buf, xs, scr + SCROFF[2], 10922, blk, sl); break;
            default: passA_body<2, 13, 14, 16>(buf, xs, scr + SCROFF[3], 10082, blk, sl); break;
        }
    } else {
        const int b2 = b - 8192;
        const int cfg = b2 >> 9, r = b2 & 511, blk = r & 15, sl = r >> 4;
        const float* xs = x + (size_t)sl * NLEN;
        switch (cfg) {
            case 0: passA_body<4, 16, 12, 16>(buf, xs, scr + SCROFF[4], 4096, blk, sl); break;
            case 1: passA_body<4, 17, 12, 20>(buf, xs, scr + SCROFF[5], 3855, blk, sl); break;
            case 2: passA_body<4, 18, 12, 20>(buf, xs, scr + SCROFF[6], 3640, blk, sl); break;
            default: passA_body<4, 19, 12, 20>(buf, xs, scr + SCROFF[7], 3449, blk, sl); break;
        }
    }
}

// ---------------- pass B ----------------
template<int BINS, int M, int CST, int HB, int LQ>
__device__ __forceinline__
void fusedB(float* __restrict__ zpg, int s, int p, int sub)
{
    constexpr int QUADS = M / 4;
    const int Q   = sub & (QUADS - 1);
    const int chi = sub >> LQ;
    const int c0  = chi * HB;
    const int h = 1 << (s - 1), S = 1 << s;
    const int q  = Q & (h - 1);
    const int G2 = (Q >> (s - 1)) << (s + 1);
    const int rA0 = G2 + q, rA1 = rA0 + h, rB0 = G2 + S + q, rB1 = rB0 + h;
    const int vo = G2 + 4 * q;
    auto mbf = [](int x, int B) { int r = x % B; return r < 0 ? r + B : r; };
    const int ba1 = mbf(c0 - q - p * h - 1, BINS);
    const int bb0 = mbf(c0 - 2 * q - p * S - 2, BINS);
    const int bb1 = mbf(c0 - 3 * q - p * (S + h) - 3, BINS);

    float fa0[HB], fa1[HB + 1], fb0[HB + 2], fb1[HB + 3];
    #pragma unroll
    for (int i = 0; i < HB; ++i) {
        int cc = c0 + i; if (cc >= BINS) cc = BINS - 1;
        fa0[i] = zpg[cc * CST + rA0];
    }
    int idx = ba1;
    #pragma unroll
    for (int i = 0; i < HB + 1; ++i) {
        fa1[i] = zpg[idx * CST + rA1];
        ++idx; if (idx == BINS) idx = 0;
    }
    idx = bb0;
    #pragma unroll
    for (int i = 0; i < HB + 2; ++i) {
        fb0[i] = zpg[idx * CST + rB0];
        ++idx; if (idx == BINS) idx = 0;
    }
    idx = bb1;
    #pragma unroll
    for (int i = 0; i < HB + 3; ++i) {
        fb1[i] = zpg[idx * CST + rB1];
        ++idx; if (idx == BINS) idx = 0;
    }
    __syncthreads();
    #pragma unroll
    for (int i2 = 0; i2 < HB; ++i2) {
        const int c = c0 + i2;
        if (c < BINS) {
            float u0 = fa0[i2] + fa1[i2 + 1];
            float u1 = fa0[i2] + fa1[i2];
            float v0c  = fb0[i2 + 2] + fb1[i2 + 3];
            float v0p  = fb0[i2 + 1] + fb1[i2 + 2];
            float v1p  = fb0[i2 + 1] + fb1[i2 + 1];
            float v1pp = fb0[i2]     + fb1[i2];
            float4 o; o.x = u0 + v0c; o.y = u0 + v0p; o.z = u1 + v1p; o.w = u1 + v1pp;
            *reinterpret_cast<float4*>(&zpg[c * CST + vo]) = o;
        }
    }
    __syncthreads();
}

template<int BINS, int K, int P, int CPAD, int OUTOFF>
__device__ __forceinline__
void passB_body(float* __restrict__ zb, float* __restrict__ s_red,
                const unsigned short* __restrict__ scrC, const float2* __restrict__ part,
                float* __restrict__ out, int R, int p_base, int sl)
{
    constexpr int S0   = 8;
    constexpr int G    = 256;
    constexpr int M    = 1 << (K - S0);   // ds2:64, ds4:16
    constexpr int TS   = K - S0;          // ds2:6,  ds4:4  (always even)
    constexpr int CST  = M + 4;
    constexpr int BCST = BINS * CST;
    constexpr int SUBW = 512 / P;         // ds2:64, ds4:32
    constexpr int LSUB = cilog2(SUBW);
    constexpr int LQB  = cilog2(M / 4);
    constexpr int CHB  = SUBW / (M / 4);
    constexpr int HB   = (BINS + CHB - 1) / CHB;

    const int t = threadIdx.x;

    if (t < 64) {
        float s = 0.f, s2 = 0.f;
        if (t < 32) { float2 pp = part[sl * STDCH + t]; s = pp.x; s2 = pp.y; }
        #pragma unroll
        for (int off = 16; off > 0; off >>= 1) {
            s  += __shfl_down(s, off, 64);
            s2 += __shfl_down(s2, off, 64);
        }
        if (t == 0) {
            const float n = (float)NLEN;
            s_red[0] = rsqrtf((s2 - s * s / n) / (n - 1.f)) * rsqrtf((float)R);
        }
    }

    // gather; fully-zero blocks (v >= vmax) were skipped by passA -> zero-fill
    {
        constexpr int RUN = P * CPAD / 4;
        constexpr int TOT = M * RUN;
        const int vmax = (R + G - 1) >> S0;
        const unsigned short* base = scrC + (size_t)sl * M * G * CPAD + (size_t)p_base * CPAD;
        for (int i = t; i < TOT; i += 512) {
            const int v = i / RUN, r = i - v * RUN;
            uint2 d = make_uint2(0u, 0u);
            if (v < vmax)
                d = *reinterpret_cast<const uint2*>(base + (size_t)v * G * CPAD + 4 * r);
            const int e0 = 4 * r;
            const int pl = e0 / CPAD, c = e0 - pl * CPAD;
            float* zp = zb + pl * BCST + v;
            if (c + 0 < BINS) zp[(c + 0) * CST] = __uint_as_float(d.x << 16);
            if (c + 1 < BINS) zp[(c + 1) * CST] = __uint_as_float(d.x & 0xFFFF0000u);
            if (c + 2 < BINS) zp[(c + 2) * CST] = __uint_as_float(d.y << 16);
            if (c + 3 < BINS) zp[(c + 3) * CST] = __uint_as_float(d.y & 0xFFFF0000u);
        }
    }
    __syncthreads();

    const int sub = t & (SUBW - 1), pg = t >> LSUB;
    const int p = p_base + pg;
    float* zpg = zb + pg * BCST;
    #pragma unroll
    for (int s = 1; s <= TS; s += 2)
        fusedB<BINS, M, CST, HB, LQB>(zpg, s, p, sub);

    constexpr int ROWS = P * M;
    if (t < ROWS) {
        const int pg2 = t >> TS;
        const int v   = t & (M - 1);
        const float* z = zb + pg2 * BCST;
        float a[BINS];
        #pragma unroll
        for (int c = 0; c < BINS; ++c) a[c] = z[c * CST + v];
        float mx = a[0];
        #pragma unroll
        for (int c = 1; c < BINS; ++c) mx = fmaxf(mx, a[c]);
        constexpr int MIDX = (BINS - 1) / 2;
        #pragma unroll
        for (int i = 0; i <= MIDX; ++i) {
            #pragma unroll
            for (int j = i + 1; j < BINS; ++j) {
                float lo = fminf(a[i], a[j]);
                float hi = fmaxf(a[i], a[j]);
                a[i] = lo; a[j] = hi;
            }
        }
        out[(size_t)sl * OUTROWS + OUTOFF + (size_t)p_base * M + t] = (mx - a[MIDX]) * s_red[0];
    }
}

__global__ __launch_bounds__(512, 6)
void passB_all(const unsigned short* __restrict__ scr, const float2* __restrict__ part,
               float* __restrict__ out)
{
    __shared__ float zb[8 * 13 * 68];   // 28.3 KB (max: ds2 P=8, BINS=13, CST=68)
    __shared__ float s_red[1];
    const int b = blockIdx.x;
    if (b < 4096) {
        const int cfg = b >> 10, r = b & 1023, pb = r & 31, sl = r >> 5;
        const int p_base = pb * 8;
        switch (cfg) {
            case 0: passB_body<10, 14, 8, 12, 0>    (zb, s_red, scr + SCROFF[0], part, out, 13107, p_base, sl); break;
            case 1: passB_body<11, 14, 8, 12, 16384>(zb, s_red, scr + SCROFF[1], part, out, 11915, p_base, sl); break;
            case 2: passB_body<12, 14, 8, 12, 32768>(zb, s_red, scr + SCROFF[2], part, out, 10922, p_base, sl); break;
            default: passB_body<13, 14, 8, 16, 49152>(zb, s_red, scr + SCROFF[3], part, out, 10082, p_base, sl); break;
        }
    } else {
        const int b2 = b - 4096;
        const int cfg = b2 >> 9, r = b2 & 511, pb = r & 15, sl = r >> 4;
        const int p_base = pb * 16;
        switch (cfg) {
            case 0: passB_body<16, 12, 16, 16, 65536>(zb, s_red, scr + SCROFF[4], part, out, 4096, p_base, sl); break;
            case 1: passB_body<17, 12, 16, 20, 69632>(zb, s_red, scr + SCROFF[5], part, out, 3855, p_base, sl); break;
            case 2: passB_body<18, 12, 16, 20, 73728>(zb, s_red, scr + SCROFF[6], part, out, 3640, p_base, sl); break;
            default: passB_body<19, 12, 16, 20, 77824>(zb, s_red, scr + SCROFF[7], part, out, 3449, p_base, sl); break;
        }
    }
}

// ---------------- host ----------------
extern "C" void kernel_launch(void* const* d_in, const int* in_sizes, int n_in,
                              void* d_out, int out_size, void* d_ws, size_t ws_size,
                              hipStream_t stream)
{
    (void)in_sizes; (void)n_in; (void)out_size; (void)ws_size;
    const float* x = (const float*)d_in[0];
    float* out  = (float*)d_out;
    float* wsf  = (float*)d_ws;
    float2* part = reinterpret_cast<float2*>(wsf + 64);        // 1024 float2
    unsigned short* scr = reinterpret_cast<unsigned short*>(wsf + 2176);  // 74.5 MB used

    hipLaunchKernelGGL(std_partial, dim3(NSEQ, STDCH), dim3(256), 0, stream, x, part);
    hipLaunchKernelGGL(passA_all, dim3(10240), dim3(256), 0, stream, x, scr);
    hipLaunchKernelGGL(passB_all, dim3(6144), dim3(512), 0, stream, scr, part, out);
}

// Round 14
// 133.809 us; speedup vs baseline: 1.2595x; 1.0649x over previous
//
#include <hip/hip_runtime.h>
#include <cmath>

// FFA regressor for MI355X — 2 dispatches: passA_all (+fused std partials), passB_all.
// R14 = R13 (=R11, measured best) + std_partial fused into passA_all's grid as
// blocks [10240,11264): std's HBM-bound reduction overlaps passA's LDS-bound
// stages (passA doesn't read the partials; passB does, and launches after).
// passA: uniform S0=8 (G=256), 256 threads, CHB=4; init + 4 radix-4 fused
// in-place stages (p=0 fusedB algebra), swz bank-swizzle, wave-local fences,
// zero-block elision. passB: fused tail stages + fused max/median/SNR.

constexpr int NSEQ    = 32;
constexpr int NLEN    = 262144;
constexpr int OUTROWS = 81920;
constexpr int STDCH   = 32;

constexpr int cilog2(int v) { int r = 0; while (v > 1) { v >>= 1; ++r; } return r; }

// scratch offsets per config, in bf16 elements (sizes: 32 * 2^K * CPAD)
constexpr size_t SCROFF[8] = {0, 6291456, 12582912, 18874368,
                              27262976, 29360128, 31981568, 34603008};

__device__ __forceinline__ unsigned bf16rne(float f) {
    unsigned u = __float_as_uint(f);
    return (u + 0x7FFFu + ((u >> 16) & 1u)) >> 16;
}
__device__ __forceinline__ unsigned pk2(float lo, float hi) {
    return bf16rne(lo) | (bf16rne(hi) << 16);
}
// bank swizzle for passA rows: bits 2-4 ^= bits 4-6 (bijective, quad-contiguous)
__device__ __forceinline__ int swz(int r) { return r ^ (((r >> 4) & 7) << 2); }

// wave-level fence (R10-proven): lanes of this wave see this wave's LDS writes
__device__ __forceinline__ void wfence()
{
    __builtin_amdgcn_sched_barrier(0);
    asm volatile("s_waitcnt lgkmcnt(0)" ::: "memory");
    __builtin_amdgcn_sched_barrier(0);
    __builtin_amdgcn_wave_barrier();
}
template<bool BAR>
__device__ __forceinline__ void stsync()
{
    if constexpr (BAR) __syncthreads();
    else wfence();
}

// ---------------- pass A: fused stages (1,2), contiguous float4 reads ----------------
template<int BINS, int G, int HB, bool BAR>
__device__ __forceinline__
void fusedA1ip(float* __restrict__ buf, int Q, int c0)
{
    constexpr int CST = G + 4;
    const int r4 = swz(4 * Q);
    float4 ff[HB + 3];
    #pragma unroll
    for (int j = 0; j < HB + 3; ++j) {
        int cc = c0 - 3 + j;
        if (cc < 0) cc += BINS;
        if (cc >= BINS) cc -= BINS;
        ff[j] = *reinterpret_cast<const float4*>(&buf[cc * CST + r4]);
    }
    stsync<BAR>();
    #pragma unroll
    for (int i = 0; i < HB; ++i) {
        const int c = c0 + i;
        if (c < BINS) {
            float4 f = ff[i + 3], fm1 = ff[i + 2], fm2 = ff[i + 1], fm3 = ff[i];
            float u0 = f.x + f.y;
            float u1 = f.x + fm1.y;
            float4 o;
            o.x = u0 + (f.z + f.w);
            o.y = u0 + (fm1.z + fm1.w);
            o.z = u1 + (fm1.z + fm2.w);
            o.w = u1 + (fm2.z + fm3.w);
            *reinterpret_cast<float4*>(&buf[c * CST + r4]) = o;
        }
    }
    stsync<BAR>();
}

// ---------------- pass A: fused stages (s, s+1), in-place ----------------
template<int BINS, int G, int HB, bool BAR>
__device__ __forceinline__
void fusedAip(float* __restrict__ buf, int s, int Q, int c0)
{
    constexpr int CST = G + 4;
    const int h = 1 << (s - 1), S = 1 << s;
    const int q  = Q & (h - 1);
    const int G2 = (Q >> (s - 1)) << (s + 1);
    const int rA0 = swz(G2 + q),     rA1 = swz(G2 + q + h);
    const int rB0 = swz(G2 + S + q), rB1 = swz(G2 + S + q + h);
    const int vo  = swz(G2 + 4 * q);
    auto mbf = [](int x) { int r = x % BINS; return r < 0 ? r + BINS : r; };
    const int ba1 = mbf(c0 - q - 1);
    const int bb0 = mbf(c0 - 2 * q - 2);
    const int bb1 = mbf(c0 - 3 * q - 3);

    float fa0[HB], fa1[HB + 1], fb0[HB + 2], fb1[HB + 3];
    #pragma unroll
    for (int i = 0; i < HB; ++i) {
        int cc = c0 + i; if (cc >= BINS) cc = BINS - 1;
        fa0[i] = buf[cc * CST + rA0];
    }
    int idx = ba1;
    #pragma unroll
    for (int i = 0; i < HB + 1; ++i) {
        fa1[i] = buf[idx * CST + rA1];
        ++idx; if (idx == BINS) idx = 0;
    }
    idx = bb0;
    #pragma unroll
    for (int i = 0; i < HB + 2; ++i) {
        fb0[i] = buf[idx * CST + rB0];
        ++idx; if (idx == BINS) idx = 0;
    }
    idx = bb1;
    #pragma unroll
    for (int i = 0; i < HB + 3; ++i) {
        fb1[i] = buf[idx * CST + rB1];
        ++idx; if (idx == BINS) idx = 0;
    }
    stsync<BAR>();
    #pragma unroll
    for (int i = 0; i < HB; ++i) {
        const int c = c0 + i;
        if (c < BINS) {
            float u0 = fa0[i] + fa1[i + 1];
            float u1 = fa0[i] + fa1[i];
            float v0c  = fb0[i + 2] + fb1[i + 3];
            float v0p  = fb0[i + 1] + fb1[i + 2];
            float v1p  = fb0[i + 1] + fb1[i + 1];
            float v1pp = fb0[i]     + fb1[i];
            float4 o; o.x = u0 + v0c; o.y = u0 + v0p; o.z = u1 + v1p; o.w = u1 + v1pp;
            *reinterpret_cast<float4*>(&buf[c * CST + vo]) = o;
        }
    }
    stsync<BAR>();
}

// ---------------- pass A body (uniform: S0=8, G=256, 256 threads) ----------------
template<int DS, int BINS, int K, int CPAD>
__device__ __forceinline__
void passA_body(float* __restrict__ buf, const float* __restrict__ xs,
                unsigned short* __restrict__ scrC, int R, int blk, int sl)
{
    constexpr int S0    = 8;
    constexpr int G     = 256;
    constexpr int M     = 1 << (K - S0);
    constexpr int CST   = G + 4;
    constexpr int QUADS = G / 4;          // 64
    constexpr int CHB   = 4;              // 256 threads / 64 quads
    constexpr int LCHB  = 2;
    constexpr int QPW   = QUADS / 4;      // 16 quads per wave (64-row span)
    constexpr int HB    = (BINS + CHB - 1) / CHB;
    const int t = threadIdx.x;

    const int fmax = max(0, min(G * BINS, R * BINS - blk * G * BINS));
    if (fmax <= 0) return;   // fully-zero block: passB zero-fills v >= ceil(R/G)

    // coalesced init (exact w=0.5 downsample)
    if constexpr (DS == 2) {
        const float4* src4 = reinterpret_cast<const float4*>(xs + 2 * (size_t)blk * G * BINS);
        constexpr int NF4 = G * BINS / 2;
        for (int i = t; i < NF4; i += 256) {
            const int f0 = 2 * i;
            if (f0 < fmax) {
                float4 v = src4[i];
                int lr = f0 / BINS, c = f0 - lr * BINS;
                buf[c * CST + swz(lr)] = 0.5f * (v.x + v.y);
                if (f0 + 1 < fmax) {
                    int c1 = c + 1, lr1 = lr;
                    if (c1 == BINS) { c1 = 0; ++lr1; }
                    buf[c1 * CST + swz(lr1)] = 0.5f * (v.z + v.w);
                }
            }
        }
    } else {
        const float4* src4 = reinterpret_cast<const float4*>(xs + 4 * (size_t)blk * G * BINS);
        constexpr int NF4 = G * BINS;
        for (int i = t; i < NF4; i += 256) {
            if (i < fmax) {
                float4 v = src4[i];
                int lr = i / BINS, c = i - lr * BINS;
                buf[c * CST + swz(lr)] = 0.5f * (v.y + v.z);
            }
        }
    }
    for (int f = fmax + t; f < G * BINS; f += 256) {
        int lr = f / BINS, c = f - lr * BINS;
        buf[c * CST + swz(lr)] = 0.f;
    }
    __syncthreads();

    // wave-local mapping: wave w owns quads [w*16, w*16+16) = rows [64w, 64w+64)
    {
        const int w = t >> 6, l = t & 63;
        const int Q  = w * QPW + (l >> LCHB);
        const int c0 = (l & (CHB - 1)) * HB;
        // groups: (1,2)->4, (3,4)->16, (5,6)->64 rows: wave-local; (7,8)->256: block
        fusedA1ip<BINS, G, HB, false>(buf, Q, c0);
        fusedAip <BINS, G, HB, false>(buf, 3, Q, c0);
        fusedAip <BINS, G, HB, false>(buf, 5, Q, c0);
        __syncthreads();
        fusedAip <BINS, G, HB, true >(buf, 7, Q, c0);
    }

    // bf16 writeout: one full row per thread, contiguous G*CPAD run per block
    {
        const int lr = swz(t);
        unsigned u[CPAD / 2];
        #pragma unroll
        for (int k = 0; k < CPAD / 2; ++k) {
            const int ca = 2 * k, cbn = 2 * k + 1;
            float fa = (ca < BINS)  ? buf[ca * CST + lr]  : 0.f;
            float fb = (cbn < BINS) ? buf[cbn * CST + lr] : 0.f;
            u[k] = pk2(fa, fb);
        }
        unsigned short* dst = scrC + ((size_t)(sl * M + blk) * G + t) * CPAD;
        if constexpr (CPAD == 16) {
            uint4* d4 = reinterpret_cast<uint4*>(dst);
            d4[0] = make_uint4(u[0], u[1], u[2], u[3]);
            d4[1] = make_uint4(u[4], u[5], u[6], u[7]);
        } else {
            uint2* d2 = reinterpret_cast<uint2*>(dst);
            #pragma unroll
            for (int k = 0; k < CPAD / 4; ++k)
                d2[k] = make_uint2(u[2 * k], u[2 * k + 1]);
        }
    }
}

// ---------------- std partial body (fused into passA_all grid) ----------------
__device__ __forceinline__
void std_body(float* __restrict__ lds, const float* __restrict__ x,
              float2* __restrict__ part, int seq, int ch)
{
    constexpr int N4 = NLEN / 4 / STDCH;
    const float4* xp = reinterpret_cast<const float4*>(x + (size_t)seq * NLEN) + (size_t)ch * N4;
    float s = 0.f, s2 = 0.f;
    for (int i = threadIdx.x; i < N4; i += 256) {
        float4 v = xp[i];
        s  += (v.x + v.y) + (v.z + v.w);
        s2 += (v.x * v.x + v.y * v.y) + (v.z * v.z + v.w * v.w);
    }
    #pragma unroll
    for (int off = 32; off > 0; off >>= 1) {
        s  += __shfl_down(s, off, 64);
        s2 += __shfl_down(s2, off, 64);
    }
    float2* ws = reinterpret_cast<float2*>(lds);
    const int w = threadIdx.x >> 6, l = threadIdx.x & 63;
    if (l == 0) ws[w] = make_float2(s, s2);
    __syncthreads();
    if (threadIdx.x == 0) {
        float a = ws[0].x + ws[1].x + ws[2].x + ws[3].x;
        float b = ws[0].y + ws[1].y + ws[2].y + ws[3].y;
        part[seq * STDCH + ch] = make_float2(a, b);
    }
}

__global__ __launch_bounds__(256, 8)
void passA_all(const float* __restrict__ x, unsigned short* __restrict__ scr,
               float2* __restrict__ part)
{
    __shared__ float buf[19 * 260];   // 19,760 B -> 8 blocks/CU (wave-capped)
    const int b = blockIdx.x;
    if (b < 8192) {
        const int cfg = b >> 11, r = b & 2047, blk = r & 63, sl = r >> 6;
        const float* xs = x + (size_t)sl * NLEN;
        switch (cfg) {
            case 0: passA_body<2, 10, 14, 12>(buf, xs, scr + SCROFF[0], 13107, blk, sl); break;
            case 1: passA_body<2, 11, 14, 12>(buf, xs, scr + SCROFF[1], 11915, blk, sl); break;
            case 2: passA_body<2, 12, 14, 12>(buf, xs, scr + SCROFF[2], 10922, blk, sl); break;
            default: passA_body<2, 13, 14, 16>(buf, xs, scr + SCROFF[3], 10082, blk, sl); break;
        }
    } else if (b < 10240) {
        const int b2 = b - 8192;
        const int cfg = b2 >> 9, r = b2 & 511, blk = r & 15, sl = r >> 4;
        const float* xs = x + (size_t)sl * NLEN;
        switch (cfg) {
            case 0: passA_body<4, 16, 12, 16>(buf, xs, scr + SCROFF[4], 4096, blk, sl); break;
            case 1: passA_body<4, 17, 12, 20>(buf, xs, scr + SCROFF[5], 3855, blk, sl); break;
            case 2: passA_body<4, 18, 12, 20>(buf, xs, scr + SCROFF[6], 3640, blk, sl); break;
            default: passA_body<4, 19, 12, 20>(buf, xs, scr + SCROFF[7], 3449, blk, sl); break;
        }
    } else {
        const int idx = b - 10240;            // 1024 std blocks
        std_body(buf, x, part, idx >> 5, idx & 31);
    }
}

// ---------------- pass B ----------------
template<int BINS, int M, int CST, int HB, int LQ>
__device__ __forceinline__
void fusedB(float* __restrict__ zpg, int s, int p, int sub)
{
    constexpr int QUADS = M / 4;
    const int Q   = sub & (QUADS - 1);
    const int chi = sub >> LQ;
    const int c0  = chi * HB;
    const int h = 1 << (s - 1), S = 1 << s;
    const int q  = Q & (h - 1);
    const int G2 = (Q >> (s - 1)) << (s + 1);
    const int rA0 = G2 + q, rA1 = rA0 + h, rB0 = G2 + S + q, rB1 = rB0 + h;
    const int vo = G2 + 4 * q;
    auto mbf = [](int x, int B) { int r = x % B; return r < 0 ? r + B : r; };
    const int ba1 = mbf(c0 - q - p * h - 1, BINS);
    const int bb0 = mbf(c0 - 2 * q - p * S - 2, BINS);
    const int bb1 = mbf(c0 - 3 * q - p * (S + h) - 3, BINS);

    float fa0[HB], fa1[HB + 1], fb0[HB + 2], fb1[HB + 3];
    #pragma unroll
    for (int i = 0; i < HB; ++i) {
        int cc = c0 + i; if (cc >= BINS) cc = BINS - 1;
        fa0[i] = zpg[cc * CST + rA0];
    }
    int idx = ba1;
    #pragma unroll
    for (int i = 0; i < HB + 1; ++i) {
        fa1[i] = zpg[idx * CST + rA1];
        ++idx; if (idx == BINS) idx = 0;
    }
    idx = bb0;
    #pragma unroll
    for (int i = 0; i < HB + 2; ++i) {
        fb0[i] = zpg[idx * CST + rB0];
        ++idx; if (idx == BINS) idx = 0;
    }
    idx = bb1;
    #pragma unroll
    for (int i = 0; i < HB + 3; ++i) {
        fb1[i] = zpg[idx * CST + rB1];
        ++idx; if (idx == BINS) idx = 0;
    }
    __syncthreads();
    #pragma unroll
    for (int i2 = 0; i2 < HB; ++i2) {
        const int c = c0 + i2;
        if (c < BINS) {
            float u0 = fa0[i2] + fa1[i2 + 1];
            float u1 = fa0[i2] + fa1[i2];
            float v0c  = fb0[i2 + 2] + fb1[i2 + 3];
            float v0p  = fb0[i2 + 1] + fb1[i2 + 2];
            float v1p  = fb0[i2 + 1] + fb1[i2 + 1];
            float v1pp = fb0[i2]     + fb1[i2];
            float4 o; o.x = u0 + v0c; o.y = u0 + v0p; o.z = u1 + v1p; o.w = u1 + v1pp;
            *reinterpret_cast<float4*>(&zpg[c * CST + vo]) = o;
        }
    }
    __syncthreads();
}

template<int BINS, int K, int P, int CPAD, int OUTOFF>
__device__ __forceinline__
void passB_body(float* __restrict__ zb, float* __restrict__ s_red,
                const unsigned short* __restrict__ scrC, const float2* __restrict__ part,
                float* __restrict__ out, int R, int p_base, int sl)
{
    constexpr int S0   = 8;
    constexpr int G    = 256;
    constexpr int M    = 1 << (K - S0);   // ds2:64, ds4:16
    constexpr int TS   = K - S0;          // ds2:6,  ds4:4  (always even)
    constexpr int CST  = M + 4;
    constexpr int BCST = BINS * CST;
    constexpr int SUBW = 512 / P;         // ds2:64, ds4:32
    constexpr int LSUB = cilog2(SUBW);
    constexpr int LQB  = cilog2(M / 4);
    constexpr int CHB  = SUBW / (M / 4);
    constexpr int HB   = (BINS + CHB - 1) / CHB;

    const int t = threadIdx.x;

    if (t < 64) {
        float s = 0.f, s2 = 0.f;
        if (t < 32) { float2 pp = part[sl * STDCH + t]; s = pp.x; s2 = pp.y; }
        #pragma unroll
        for (int off = 16; off > 0; off >>= 1) {
            s  += __shfl_down(s, off, 64);
            s2 += __shfl_down(s2, off, 64);
        }
        if (t == 0) {
            const float n = (float)NLEN;
            s_red[0] = rsqrtf((s2 - s * s / n) / (n - 1.f)) * rsqrtf((float)R);
        }
    }

    // gather; fully-zero blocks (v >= vmax) were skipped by passA -> zero-fill
    {
        constexpr int RUN = P * CPAD / 4;
        constexpr int TOT = M * RUN;
        const int vmax = (R + G - 1) >> S0;
        const unsigned short* base = scrC + (size_t)sl * M * G * CPAD + (size_t)p_base * CPAD;
        for (int i = t; i < TOT; i += 512) {
            const int v = i / RUN, r = i - v * RUN;
            uint2 d = make_uint2(0u, 0u);
            if (v < vmax)
                d = *reinterpret_cast<const uint2*>(base + (size_t)v * G * CPAD + 4 * r);
            const int e0 = 4 * r;
            const int pl = e0 / CPAD, c = e0 - pl * CPAD;
            float* zp = zb + pl * BCST + v;
            if (c + 0 < BINS) zp[(c + 0) * CST] = __uint_as_float(d.x << 16);
            if (c + 1 < BINS) zp[(c + 1) * CST] = __uint_as_float(d.x & 0xFFFF0000u);
            if (c + 2 < BINS) zp[(c + 2) * CST] = __uint_as_float(d.y << 16);
            if (c + 3 < BINS) zp[(c + 3) * CST] = __uint_as_float(d.y & 0xFFFF0000u);
        }
    }
    __syncthreads();

    const int sub = t & (SUBW - 1), pg = t >> LSUB;
    const int p = p_base + pg;
    float* zpg = zb + pg * BCST;
    #pragma unroll
    for (int s = 1; s <= TS; s += 2)
        fusedB<BINS, M, CST, HB, LQB>(zpg, s, p, sub);

    constexpr int ROWS = P * M;
    if (t < ROWS) {
        const int pg2 = t >> TS;
        const int v   = t & (M - 1);
        const float* z = zb + pg2 * BCST;
        float a[BINS];
        #pragma unroll
        for (int c = 0; c < BINS; ++c) a[c] = z[c * CST + v];
        float mx = a[0];
        #pragma unroll
        for (int c = 1; c < BINS; ++c) mx = fmaxf(mx, a[c]);
        constexpr int MIDX = (BINS - 1) / 2;
        #pragma unroll
        for (int i = 0; i <= MIDX; ++i) {
            #pragma unroll
            for (int j = i + 1; j < BINS; ++j) {
                float lo = fminf(a[i], a[j]);
                float hi = fmaxf(a[i], a[j]);
                a[i] = lo; a[j] = hi;
            }
        }
        out[(size_t)sl * OUTROWS + OUTOFF + (size_t)p_base * M + t] = (mx - a[MIDX]) * s_red[0];
    }
}

__global__ __launch_bounds__(512, 6)
void passB_all(const unsigned short* __restrict__ scr, const float2* __restrict__ part,
               float* __restrict__ out)
{
    __shared__ float zb[8 * 13 * 68];   // 28.3 KB (max: ds2 P=8, BINS=13, CST=68)
    __shared__ float s_red[1];
    const int b = blockIdx.x;
    if (b < 4096) {
        const int cfg = b >> 10, r = b & 1023, pb = r & 31, sl = r >> 5;
        const int p_base = pb * 8;
        switch (cfg) {
            case 0: passB_body<10, 14, 8, 12, 0>    (zb, s_red, scr + SCROFF[0], part, out, 13107, p_base, sl); break;
            case 1: passB_body<11, 14, 8, 12, 16384>(zb, s_red, scr + SCROFF[1], part, out, 11915, p_base, sl); break;
            case 2: passB_body<12, 14, 8, 12, 32768>(zb, s_red, scr + SCROFF[2], part, out, 10922, p_base, sl); break;
            default: passB_body<13, 14, 8, 16, 49152>(zb, s_red, scr + SCROFF[3], part, out, 10082, p_base, sl); break;
        }
    } else {
        const int b2 = b - 4096;
        const int cfg = b2 >> 9, r = b2 & 511, pb = r & 15, sl = r >> 4;
        const int p_base = pb * 16;
        switch (cfg) {
            case 0: passB_body<16, 12, 16, 16, 65536>(zb, s_red, scr + SCROFF[4], part, out, 4096, p_base, sl); break;
            case 1: passB_body<17, 12, 16, 20, 69632>(zb, s_red, scr + SCROFF[5], part, out, 3855, p_base, sl); break;
            case 2: passB_body<18, 12, 16, 20, 73728>(zb, s_red, scr + SCROFF[6], part, out, 3640, p_base, sl); break;
            default: passB_body<19, 12, 16, 20, 77824>(zb, s_red, scr + SCROFF[7], part, out, 3449, p_base, sl); break;
        }
    }
}

// ---------------- host ----------------
extern "C" void kernel_launch(void* const* d_in, const int* in_sizes, int n_in,
                              void* d_out, int out_size, void* d_ws, size_t ws_size,
                              hipStream_t stream)
{
    (void)in_sizes; (void)n_in; (void)out_size; (void)ws_size;
    const float* x = (const float*)d_in[0];
    float* out  = (float*)d_out;
    float* wsf  = (float*)d_ws;
    float2* part = reinterpret_cast<float2*>(wsf + 64);        // 1024 float2
    unsigned short* scr = reinterpret_cast<unsigned short*>(wsf + 2176);  // 74.5 MB used

    hipLaunchKernelGGL(passA_all, dim3(10240 + NSEQ * STDCH), dim3(256), 0, stream,
                       x, scr, part);
    hipLaunchKernelGGL(passB_all, dim3(6144), dim3(512), 0, stream, scr, part, out);
}